// Round 3
// baseline (355.545 us; speedup 1.0000x reference)
//
#include <hip/hip_runtime.h>
#include <hip/hip_bf16.h>

#define NTOK 196
#define CDIM 768
#define BSAMP 256
#define NCLS 701
#define NCLSP 704

typedef __attribute__((ext_vector_type(8))) short bf16x8;
typedef __attribute__((ext_vector_type(4))) float f32x4;

__device__ __forceinline__ void add4(float4& a, const float4& b) {
  a.x += b.x; a.y += b.y; a.z += b.z; a.w += b.w;
}

// One block per (sample, branch) task. 512 threads = 8 waves.
// Phase A : pure-streaming read of the 196x768 tile. Per token, each lane
//           accumulates its 12 floats into column accumulators and writes a
//           single scalar partial to LDS (tokpart[t][lane], stride 65 ->
//           conflict-free). NO cross-lane ops in the hot loop, so loads from
//           both unrolled tokens stay in flight (launch_bounds(512,4) gives
//           the allocator 128 VGPRs).
// Phase A2: per-token 64-lane reduce: 1 ds_read + the same 6-step butterfly
//           as R2 -> Msh bitwise-identical to the passing R2 kernel.
// Phase B : normalize, O(N^2) stable rank, gap argmax -> k (unchanged).
// Phase C : compact the SMALLER token set, batched re-reads (L2-resident);
//           other side = S_all - subset. partS/partT overlay dead tokpart.
__global__ __launch_bounds__(512, 4) void sgm_kernel(const float* __restrict__ x1,
                                                     const float* __restrict__ x2,
                                                     __hip_bfloat16* __restrict__ Vb) {
  const int task = blockIdx.x;
  const int s  = task & 255;
  const int br = task >> 8;
  const float* __restrict__ feats = (br ? x2 : x1) + (size_t)s * (NTOK * CDIM);

  const int tid  = threadIdx.x;
  const int lane = tid & 63;
  const int wv   = tid >> 6;   // 0..7

  __shared__ __align__(16) float tokpart[NTOK][65];  // 50,960 B; overlaid later
  __shared__ float Msh[NTOK];
  __shared__ float Mn[NTOK];
  __shared__ float sortedv[NTOK];
  __shared__ int   rnk[NTOK];
  __shared__ int   list[NTOK];
  __shared__ float redmin[8], redmax[8];
  __shared__ int   kSh;
  __shared__ int   cntSh;
  // overlay (used only after phase C; tokpart is dead by then):
  float* partS = &tokpart[0][0];          // [8][CDIM]
  float* partT = partS + 8 * CDIM;        // [8][CDIM]; 12288 floats <= 12740

  // ---------------- Phase A (streaming, no cross-lane ops) ----------------
  float4 acc0 = {0,0,0,0}, acc1 = {0,0,0,0}, acc2 = {0,0,0,0};
  const float* lanebase = feats + lane * 4;

  int t = wv;
  for (; t + 8 < NTOK; t += 16) {          // 2 tokens unrolled: 6 loads live
    const float* pA = lanebase + (size_t)t * CDIM;
    const float* pB = pA + (size_t)8 * CDIM;
    const float4 a0 = *(const float4*)(pA);
    const float4 a1 = *(const float4*)(pA + 256);
    const float4 a2 = *(const float4*)(pA + 512);
    const float4 b0 = *(const float4*)(pB);
    const float4 b1 = *(const float4*)(pB + 256);
    const float4 b2 = *(const float4*)(pB + 512);
    add4(acc0, a0); add4(acc1, a1); add4(acc2, a2);
    const float ea = ((a0.x + a0.y) + (a0.z + a0.w))
                   + ((a1.x + a1.y) + (a1.z + a1.w))
                   + ((a2.x + a2.y) + (a2.z + a2.w));
    tokpart[t][lane] = ea;
    add4(acc0, b0); add4(acc1, b1); add4(acc2, b2);
    const float eb = ((b0.x + b0.y) + (b0.z + b0.w))
                   + ((b1.x + b1.y) + (b1.z + b1.w))
                   + ((b2.x + b2.y) + (b2.z + b2.w));
    tokpart[t + 8][lane] = eb;
  }
  if (t < NTOK) {                          // tail token (waves 0..3)
    const float* pA = lanebase + (size_t)t * CDIM;
    const float4 a0 = *(const float4*)(pA);
    const float4 a1 = *(const float4*)(pA + 256);
    const float4 a2 = *(const float4*)(pA + 512);
    add4(acc0, a0); add4(acc1, a1); add4(acc2, a2);
    const float ea = ((a0.x + a0.y) + (a0.z + a0.w))
                   + ((a1.x + a1.y) + (a1.z + a1.w))
                   + ((a2.x + a2.y) + (a2.z + a2.w));
    tokpart[t][lane] = ea;
  }
  if (tid == 0) cntSh = 0;
  __syncthreads();

  // ---------------- Phase A2 (per-token butterfly, == R2's Msh) -----------
  for (int tt = wv; tt < NTOK; tt += 8) {
    float e = tokpart[tt][lane];
    #pragma unroll
    for (int off = 32; off; off >>= 1) e += __shfl_xor(e, off);
    if (lane == 0) Msh[tt] = e;
  }
  __syncthreads();

  // ---------------- Phase B ----------------
  float vmn = (tid < NTOK) ? Msh[tid] :  1e30f;
  float vmx = (tid < NTOK) ? Msh[tid] : -1e30f;
  #pragma unroll
  for (int off = 32; off; off >>= 1) {
    vmn = fminf(vmn, __shfl_xor(vmn, off));
    vmx = fmaxf(vmx, __shfl_xor(vmx, off));
  }
  if (lane == 0) { redmin[wv] = vmn; redmax[wv] = vmx; }
  __syncthreads();
  float mn = redmin[0], mx = redmax[0];
  #pragma unroll
  for (int i = 1; i < 8; i++) { mn = fminf(mn, redmin[i]); mx = fmaxf(mx, redmax[i]); }
  const float rng = mx - mn;
  if (tid < NTOK) Mn[tid] = (Msh[tid] - mn) / rng;   // exact IEEE div, like ref
  __syncthreads();

  if (tid < NTOK) {
    const float mv = Mn[tid];
    int r = 0;
    for (int u = 0; u < NTOK; u++) {
      const float o = Mn[u];
      r += (o < mv) || (o == mv && u < tid);   // stable argsort tie-break
    }
    sortedv[r] = mv;
    rnk[tid] = r;
  }
  __syncthreads();

  if (tid < 64) {
    float bd = -1.0f; int bj = NTOK;
    for (int j = lane; j < NTOK - 1; j += 64) {
      const float sj = sortedv[j];
      const float d = (sj == 0.0f) ? 0.0f : (sortedv[j + 1] - sj);
      if (d > bd || (d == bd && j < bj)) { bd = d; bj = j; }
    }
    #pragma unroll
    for (int off = 32; off; off >>= 1) {
      const float od = __shfl_xor(bd, off);
      const int   oj = __shfl_xor(bj, off);
      if (od > bd || (od == bd && oj < bj)) { bd = od; bj = oj; }
    }
    if (lane == 0) kSh = bj;   // first-occurrence argmax
  }
  __syncthreads();

  const int k = kSh;
  const bool takeFg = (k <= NTOK / 2);

  // compact the smaller set's token indices (order irrelevant for the sum)
  if (tid < NTOK) {
    const int r = rnk[tid];
    const bool inSet = takeFg ? (r < k) : (r >= k);
    if (inSet) { int p = atomicAdd(&cntSh, 1); list[p] = tid; }
  }
  __syncthreads();
  const int m = cntSh;

  // ---------------- Phase C (batched over list) ----------------
  float4 t0a = {0,0,0,0}, t1a = {0,0,0,0}, t2a = {0,0,0,0};
  for (int i0 = wv * 4; i0 < m; i0 += 32) {
    const int nb = m - i0;   // wave-uniform; >=1
    float4 r[4][3];
    #pragma unroll
    for (int j = 0; j < 4; j++) {
      if (j < nb) {
        const int tk = list[i0 + j];
        const float* p = lanebase + (size_t)tk * CDIM;
        #pragma unroll
        for (int g = 0; g < 3; g++) r[j][g] = *(const float4*)(p + g * 256);
      }
    }
    #pragma unroll
    for (int j = 0; j < 4; j++) {
      if (j < nb) { add4(t0a, r[j][0]); add4(t1a, r[j][1]); add4(t2a, r[j][2]); }
    }
  }
  __syncthreads();   // tokpart fully dead; safe to overlay

  const int base = lane * 4;
  *(float4*)&partS[wv * CDIM + base      ] = acc0;
  *(float4*)&partS[wv * CDIM + base + 256] = acc1;
  *(float4*)&partS[wv * CDIM + base + 512] = acc2;
  *(float4*)&partT[wv * CDIM + base      ] = t0a;
  *(float4*)&partT[wv * CDIM + base + 256] = t1a;
  *(float4*)&partT[wv * CDIM + base + 512] = t2a;
  __syncthreads();

  const float fgc = (float)(k > 1 ? k : 1);
  const float bgc = (float)((NTOK - k) > 1 ? (NTOK - k) : 1);
  const size_t rowFg = (size_t)(2 * br + 1) * BSAMP + s;
  const size_t rowBg = (size_t)(2 * br    ) * BSAMP + s;
  for (int c = tid; c < CDIM; c += 512) {
    float S = 0.0f, T = 0.0f;
    #pragma unroll
    for (int w = 0; w < 8; w++) { S += partS[w * CDIM + c]; T += partT[w * CDIM + c]; }
    float fg, bg;
    if (takeFg) { fg = T;     bg = S - T; }
    else        { bg = T;     fg = S - T; }
    Vb[rowFg * CDIM + c] = __float2bfloat16(fg / fgc);
    Vb[rowBg * CDIM + c] = __float2bfloat16(bg / bgc);
  }
}

// W [768][701] fp32 -> WT [704][768] bf16 (rows 701..703 zero-padded).
__global__ __launch_bounds__(256) void wt_kernel(const float* __restrict__ W,
                                                 __hip_bfloat16* __restrict__ WT) {
  __shared__ float tile[32][33];
  const int c0 = blockIdx.x * 32;   // class cols of W
  const int k0 = blockIdx.y * 32;   // k rows of W
  const int tx = threadIdx.x & 31;
  const int ty = threadIdx.x >> 5;  // 0..7
  #pragma unroll
  for (int i = 0; i < 4; i++) {
    const int kr = ty + i * 8;      // 0..31
    const int c = c0 + tx;
    tile[kr][tx] = (c < NCLS) ? W[(size_t)(k0 + kr) * NCLS + c] : 0.0f;
  }
  __syncthreads();
  #pragma unroll
  for (int i = 0; i < 4; i++) {
    const int cr = ty + i * 8;      // class row within tile
    const int cls = c0 + cr;        // < 704 always
    WT[(size_t)cls * CDIM + k0 + tx] = __float2bfloat16(tile[tx][cr]);
  }
}

// Vb [1024][768] bf16 x WT [704][768] bf16 -> out [1024][701] fp32 (+bias).
// One 16x16 tile per wave via mfma_f32_16x16x32_bf16; K fully unrolled.
__global__ __launch_bounds__(256) void mfma_gemm(const __hip_bfloat16* __restrict__ Vb,
                                                 const __hip_bfloat16* __restrict__ WT,
                                                 const float* __restrict__ bias,
                                                 float* __restrict__ out) {
  const int w = blockIdx.x * 4 + (threadIdx.x >> 6);   // 0..2815
  const int lane = threadIdx.x & 63;
  const int tr = w / (NCLSP / 16);   // 0..63
  const int tc = w % (NCLSP / 16);   // 0..43
  const int m0 = tr * 16;
  const int n0 = tc * 16;
  const int ko = (lane >> 4) * 8;

  const short* aptr = (const short*)Vb + (size_t)(m0 + (lane & 15)) * CDIM + ko;
  const short* bptr = (const short*)WT + (size_t)(n0 + (lane & 15)) * CDIM + ko;

  f32x4 acc = {0.f, 0.f, 0.f, 0.f};
  #pragma unroll
  for (int k0 = 0; k0 < CDIM; k0 += 32) {
    const bf16x8 af = *(const bf16x8*)(aptr + k0);
    const bf16x8 bf = *(const bf16x8*)(bptr + k0);
    acc = __builtin_amdgcn_mfma_f32_16x16x32_bf16(af, bf, acc, 0, 0, 0);
  }

  const int crow = m0 + (lane >> 4) * 4;
  const int ccol = n0 + (lane & 15);
  if (ccol < NCLS) {
    const float bv = bias[ccol];
    #pragma unroll
    for (int r = 0; r < 4; r++)
      out[(size_t)(crow + r) * NCLS + ccol] = acc[r] + bv;
  }
}

extern "C" void kernel_launch(void* const* d_in, const int* in_sizes, int n_in,
                              void* d_out, int out_size, void* d_ws, size_t ws_size,
                              hipStream_t stream) {
  const float* x1 = (const float*)d_in[0];
  const float* x2 = (const float*)d_in[1];
  const float* W  = (const float*)d_in[2];
  const float* b  = (const float*)d_in[3];
  float* out = (float*)d_out;

  __hip_bfloat16* Vb = (__hip_bfloat16*)d_ws;                            // 1.5 MB
  __hip_bfloat16* WT = (__hip_bfloat16*)((char*)d_ws + 1024 * CDIM * 2); // 1.08 MB

  sgm_kernel<<<512, 512, 0, stream>>>(x1, x2, Vb);
  wt_kernel<<<dim3(22, 24), 256, 0, stream>>>(W, WT);
  mfma_gemm<<<704, 256, 0, stream>>>(Vb, WT, b, out);
}

// Round 4
// 353.309 us; speedup vs baseline: 1.0063x; 1.0063x over previous
//
#include <hip/hip_runtime.h>
#include <hip/hip_bf16.h>

#define NTOK 196
#define QTOK 49
#define CDIM 768
#define BSAMP 256
#define NTASK 512
#define NCLS 701
#define NCLSP 704

typedef __attribute__((ext_vector_type(8))) short bf16x8;
typedef __attribute__((ext_vector_type(4))) float f32x4;

__device__ __forceinline__ void add4(float4& a, const float4& b) {
  a.x += b.x; a.y += b.y; a.z += b.z; a.w += b.w;
}

// ---------------------------------------------------------------------------
// Kernel 1: pure streaming pass at MAX occupancy.
// 2048 blocks x 256 threads = 8 blocks/CU (12 KB LDS, <=64 VGPR via
// launch_bounds(256,8)) -> 32 waves/CU. Block b handles quarter q=b&3 of
// task b>>2 (49 tokens). Produces per-token energies Mg (summation tree
// bitwise-identical to the R2/R3 passing kernels -> same k downstream) and
// per-block column partial sums Sg[b][768].
// ---------------------------------------------------------------------------
__global__ __launch_bounds__(256, 8) void phaseA_kernel(const float* __restrict__ x1,
                                                        const float* __restrict__ x2,
                                                        float* __restrict__ Mg,
                                                        float* __restrict__ Sg) {
  const int b    = blockIdx.x;
  const int task = b >> 2;
  const int q    = b & 3;
  const int s    = task & 255;
  const int br   = task >> 8;
  const float* __restrict__ feats = (br ? x2 : x1) + (size_t)s * (NTOK * CDIM);

  const int tid  = threadIdx.x;
  const int lane = tid & 63;
  const int wv   = tid >> 6;   // 0..3

  __shared__ float colred[4][CDIM];   // 12 KB

  float4 a0 = {0,0,0,0}, a1 = {0,0,0,0}, a2 = {0,0,0,0};
  const float* lanebase = feats + (size_t)(q * QTOK) * CDIM + lane * 4;

  for (int tl = wv; tl < QTOK; tl += 4) {
    const float* p = lanebase + (size_t)tl * CDIM;
    const float4 r0 = *(const float4*)(p);
    const float4 r1 = *(const float4*)(p + 256);
    const float4 r2 = *(const float4*)(p + 512);
    add4(a0, r0); add4(a1, r1); add4(a2, r2);
    float e = ((r0.x + r0.y) + (r0.z + r0.w))
            + ((r1.x + r1.y) + (r1.z + r1.w))
            + ((r2.x + r2.y) + (r2.z + r2.w));
    #pragma unroll
    for (int off = 32; off; off >>= 1) e += __shfl_xor(e, off);
    if (lane == 0) Mg[(size_t)task * NTOK + q * QTOK + tl] = e;
  }

  *(float4*)&colred[wv][lane * 4      ] = a0;
  *(float4*)&colred[wv][lane * 4 + 256] = a1;
  *(float4*)&colred[wv][lane * 4 + 512] = a2;
  __syncthreads();
  for (int c = tid; c < CDIM; c += 256) {
    // fixed order -> deterministic across replays
    Sg[(size_t)b * CDIM + c] = (colred[0][c] + colred[1][c])
                             + (colred[2][c] + colred[3][c]);
  }
}

// ---------------------------------------------------------------------------
// Kernel 2: per-task rank/split + phase C. 512 blocks x 256 threads, ~16 KB
// LDS. Reads Mg (196 floats) + 4 quarter column-partials; rank & gap-argmax
// identical to the passing R2/R3 code; re-reads only the SMALLER token set
// (typically a handful of tokens, L2/L3-resident); writes Vb in bf16.
// ---------------------------------------------------------------------------
__global__ __launch_bounds__(256) void sgm2_kernel(const float* __restrict__ x1,
                                                   const float* __restrict__ x2,
                                                   const float* __restrict__ Mg,
                                                   const float* __restrict__ Sg,
                                                   __hip_bfloat16* __restrict__ Vb) {
  const int task = blockIdx.x;
  const int s  = task & 255;
  const int br = task >> 8;
  const float* __restrict__ feats = (br ? x2 : x1) + (size_t)s * (NTOK * CDIM);

  const int tid  = threadIdx.x;
  const int lane = tid & 63;
  const int wv   = tid >> 6;   // 0..3

  __shared__ float Msh[NTOK];
  __shared__ float Mn[NTOK];
  __shared__ float sortedv[NTOK];
  __shared__ int   rnk[NTOK];
  __shared__ int   list[NTOK];
  __shared__ float redmin[4], redmax[4];
  __shared__ int   kSh;
  __shared__ int   cntSh;
  __shared__ float partT[4][CDIM];   // 12 KB

  if (tid < NTOK) Msh[tid] = Mg[(size_t)task * NTOK + tid];
  if (tid == 0) cntSh = 0;

  // total column sums for this task (kept in registers)
  float srow[3];
  #pragma unroll
  for (int j = 0; j < 3; j++) {
    const int c = tid + j * 256;
    const float* sq = Sg + (size_t)(task * 4) * CDIM + c;
    srow[j] = (sq[0] + sq[CDIM]) + (sq[2 * CDIM] + sq[3 * CDIM]);
  }
  __syncthreads();

  // min/max over energies
  float vmn = (tid < NTOK) ? Msh[tid] :  1e30f;
  float vmx = (tid < NTOK) ? Msh[tid] : -1e30f;
  #pragma unroll
  for (int off = 32; off; off >>= 1) {
    vmn = fminf(vmn, __shfl_xor(vmn, off));
    vmx = fmaxf(vmx, __shfl_xor(vmx, off));
  }
  if (lane == 0) { redmin[wv] = vmn; redmax[wv] = vmx; }
  __syncthreads();
  float mn = redmin[0], mx = redmax[0];
  #pragma unroll
  for (int i = 1; i < 4; i++) { mn = fminf(mn, redmin[i]); mx = fmaxf(mx, redmax[i]); }
  const float rng = mx - mn;
  if (tid < NTOK) Mn[tid] = (Msh[tid] - mn) / rng;   // exact IEEE div, like ref
  __syncthreads();

  // O(N^2) stable rank
  if (tid < NTOK) {
    const float mv = Mn[tid];
    int r = 0;
    for (int u = 0; u < NTOK; u++) {
      const float o = Mn[u];
      r += (o < mv) || (o == mv && u < tid);   // stable argsort tie-break
    }
    sortedv[r] = mv;
    rnk[tid] = r;
  }
  __syncthreads();

  // gap argmax (first occurrence)
  if (tid < 64) {
    float bd = -1.0f; int bj = NTOK;
    for (int j = lane; j < NTOK - 1; j += 64) {
      const float sj = sortedv[j];
      const float d = (sj == 0.0f) ? 0.0f : (sortedv[j + 1] - sj);
      if (d > bd || (d == bd && j < bj)) { bd = d; bj = j; }
    }
    #pragma unroll
    for (int off = 32; off; off >>= 1) {
      const float od = __shfl_xor(bd, off);
      const int   oj = __shfl_xor(bj, off);
      if (od > bd || (od == bd && oj < bj)) { bd = od; bj = oj; }
    }
    if (lane == 0) kSh = bj;
  }
  __syncthreads();

  const int k = kSh;
  const bool takeFg = (k <= NTOK / 2);

  // compact the smaller set's token indices (order irrelevant for the sum)
  if (tid < NTOK) {
    const int r = rnk[tid];
    const bool inSet = takeFg ? (r < k) : (r >= k);
    if (inSet) { int p = atomicAdd(&cntSh, 1); list[p] = tid; }
  }
  __syncthreads();
  const int m = cntSh;

  // phase C: batched re-read of the subset
  float4 t0a = {0,0,0,0}, t1a = {0,0,0,0}, t2a = {0,0,0,0};
  const float* lanebase = feats + lane * 4;
  for (int i0 = wv * 4; i0 < m; i0 += 16) {
    const int nb = m - i0;   // wave-uniform; >=1
    float4 r[4][3];
    #pragma unroll
    for (int j = 0; j < 4; j++) {
      if (j < nb) {
        const int tk = list[i0 + j];
        const float* p = lanebase + (size_t)tk * CDIM;
        #pragma unroll
        for (int g = 0; g < 3; g++) r[j][g] = *(const float4*)(p + g * 256);
      }
    }
    #pragma unroll
    for (int j = 0; j < 4; j++) {
      if (j < nb) { add4(t0a, r[j][0]); add4(t1a, r[j][1]); add4(t2a, r[j][2]); }
    }
  }

  *(float4*)&partT[wv][lane * 4      ] = t0a;
  *(float4*)&partT[wv][lane * 4 + 256] = t1a;
  *(float4*)&partT[wv][lane * 4 + 512] = t2a;
  __syncthreads();

  const float fgc = (float)(k > 1 ? k : 1);
  const float bgc = (float)((NTOK - k) > 1 ? (NTOK - k) : 1);
  const size_t rowFg = (size_t)(2 * br + 1) * BSAMP + s;
  const size_t rowBg = (size_t)(2 * br    ) * BSAMP + s;
  #pragma unroll
  for (int j = 0; j < 3; j++) {
    const int c = tid + j * 256;
    const float T = (partT[0][c] + partT[1][c]) + (partT[2][c] + partT[3][c]);
    const float S = srow[j];
    float fg, bg;
    if (takeFg) { fg = T;     bg = S - T; }
    else        { bg = T;     fg = S - T; }
    Vb[rowFg * CDIM + c] = __float2bfloat16(fg / fgc);
    Vb[rowBg * CDIM + c] = __float2bfloat16(bg / bgc);
  }
}

// W [768][701] fp32 -> WT [704][768] bf16 (rows 701..703 zero-padded).
__global__ __launch_bounds__(256) void wt_kernel(const float* __restrict__ W,
                                                 __hip_bfloat16* __restrict__ WT) {
  __shared__ float tile[32][33];
  const int c0 = blockIdx.x * 32;   // class cols of W
  const int k0 = blockIdx.y * 32;   // k rows of W
  const int tx = threadIdx.x & 31;
  const int ty = threadIdx.x >> 5;  // 0..7
  #pragma unroll
  for (int i = 0; i < 4; i++) {
    const int kr = ty + i * 8;      // 0..31
    const int c = c0 + tx;
    tile[kr][tx] = (c < NCLS) ? W[(size_t)(k0 + kr) * NCLS + c] : 0.0f;
  }
  __syncthreads();
  #pragma unroll
  for (int i = 0; i < 4; i++) {
    const int cr = ty + i * 8;      // class row within tile
    const int cls = c0 + cr;        // < 704 always
    WT[(size_t)cls * CDIM + k0 + tx] = __float2bfloat16(tile[tx][cr]);
  }
}

// Vb [1024][768] bf16 x WT [704][768] bf16 -> out [1024][701] fp32 (+bias).
// One 16x16 tile per wave via mfma_f32_16x16x32_bf16; K fully unrolled.
__global__ __launch_bounds__(256) void mfma_gemm(const __hip_bfloat16* __restrict__ Vb,
                                                 const __hip_bfloat16* __restrict__ WT,
                                                 const float* __restrict__ bias,
                                                 float* __restrict__ out) {
  const int w = blockIdx.x * 4 + (threadIdx.x >> 6);   // 0..2815
  const int lane = threadIdx.x & 63;
  const int tr = w / (NCLSP / 16);   // 0..63
  const int tc = w % (NCLSP / 16);   // 0..43
  const int m0 = tr * 16;
  const int n0 = tc * 16;
  const int ko = (lane >> 4) * 8;

  const short* aptr = (const short*)Vb + (size_t)(m0 + (lane & 15)) * CDIM + ko;
  const short* bptr = (const short*)WT + (size_t)(n0 + (lane & 15)) * CDIM + ko;

  f32x4 acc = {0.f, 0.f, 0.f, 0.f};
  #pragma unroll
  for (int k0 = 0; k0 < CDIM; k0 += 32) {
    const bf16x8 af = *(const bf16x8*)(aptr + k0);
    const bf16x8 bf = *(const bf16x8*)(bptr + k0);
    acc = __builtin_amdgcn_mfma_f32_16x16x32_bf16(af, bf, acc, 0, 0, 0);
  }

  const int crow = m0 + (lane >> 4) * 4;
  const int ccol = n0 + (lane & 15);
  if (ccol < NCLS) {
    const float bv = bias[ccol];
    #pragma unroll
    for (int r = 0; r < 4; r++)
      out[(size_t)(crow + r) * NCLS + ccol] = acc[r] + bv;
  }
}

extern "C" void kernel_launch(void* const* d_in, const int* in_sizes, int n_in,
                              void* d_out, int out_size, void* d_ws, size_t ws_size,
                              hipStream_t stream) {
  const float* x1 = (const float*)d_in[0];
  const float* x2 = (const float*)d_in[1];
  const float* W  = (const float*)d_in[2];
  const float* b  = (const float*)d_in[3];
  float* out = (float*)d_out;

  char* ws = (char*)d_ws;
  __hip_bfloat16* Vb = (__hip_bfloat16*)ws;                      // 1,572,864 B
  __hip_bfloat16* WT = (__hip_bfloat16*)(ws + 1572864);          // 1,081,344 B
  float* Mg = (float*)(ws + 1572864 + 1081344);                  //   401,408 B
  float* Sg = (float*)(ws + 1572864 + 1081344 + 401408);         // 6,291,456 B  (~9.3 MB total)

  phaseA_kernel<<<2048, 256, 0, stream>>>(x1, x2, Mg, Sg);
  sgm2_kernel<<<512, 256, 0, stream>>>(x1, x2, Mg, Sg, Vb);
  wt_kernel<<<dim3(22, 24), 256, 0, stream>>>(W, WT);
  mfma_gemm<<<704, 256, 0, stream>>>(Vb, WT, b, out);
}